// Round 8
// baseline (197.596 us; speedup 1.0000x reference)
//
#include <hip/hip_runtime.h>
#include <math.h>

// YOLO loss: pred/target (BATCH,7,7,30) f32, choice (BATCH,7,7) i32
// -> 4 scalars (loc, cls, obj, noobj).
// Round-8: r7 (non-temporal staging loads) lifted read rate 2.5->3.5 TB/s;
// yolo_main dropped below the harness's 56us ws-poison fills. Remaining
// theory: burst-issue gap — each block issues its 9-load burst once per
// chunk then idles through ds_write+compute. Fix: prefetch depth 2
// (ping-pong register chunks rA/rB, +32 VGPR stays <=128 so occupancy is
// unchanged at 16 waves/CU) + GRID=1024 to match true 4-blocks/CU residency.
// Keeps: nt loads (r7), coalesced float4->LDS staging (r2), no atomics (r3).

typedef float vf4 __attribute__((ext_vector_type(4)));   // nt-load compatible

constexpr int NCH = 30;    // 5*B + C
constexpr int CC  = 20;    // classes
constexpr int ROW = 8;     // floats per block's partial row (32 B)
constexpr int T   = 256;   // threads per block (4 waves)
constexpr int CPB = 128;   // cells per chunk
constexpr int NF4 = CPB * NCH * 2 / 4;  // 1920 vf4 per chunk (pred+target)
constexpr int HF4 = NF4 / 2;            // 960: pred/target boundary
constexpr int GRID = 1024; // 4 blocks/CU * 256 CU (VGPR-capped residency)

__device__ __forceinline__ void issue_chunk(
    const float* __restrict__ pred, const float* __restrict__ target,
    const int* __restrict__ choice, int cc, int ncells, int tid,
    vf4 (&r)[8], int& ci)
{
    long long base = (long long)cc * CPB;
    if (base + CPB <= (long long)ncells) {
        const vf4* Pb = (const vf4*)(pred + base * NCH);
        const vf4* Tb = (const vf4*)(target + base * NCH);
        #pragma unroll
        for (int j = 0; j < 8; ++j) {
            int k = j * T + tid;            // guards wave-uniform (T mult of 64)
            if (k < NF4)
                r[j] = (k < HF4) ? __builtin_nontemporal_load(&Pb[k])
                                 : __builtin_nontemporal_load(&Tb[k - HF4]);
        }
    } else {
        int nfl = (int)(ncells - base) * NCH;   // valid floats per array
        const float* Pf = pred + base * NCH;
        const float* Tf = target + base * NCH;
        #pragma unroll
        for (int j = 0; j < 8; ++j) {
            int k = j * T + tid;
            vf4 v = (vf4)(0.f, 0.f, 0.f, 0.f);
            if (k < NF4) {
                int kk = (k < HF4) ? k : k - HF4;
                const float* src = (k < HF4) ? Pf : Tf;
                int b = 4 * kk;
                if (b + 0 < nfl) v.x = src[b + 0];
                if (b + 1 < nfl) v.y = src[b + 1];
                if (b + 2 < nfl) v.z = src[b + 2];
                if (b + 3 < nfl) v.w = src[b + 3];
            }
            r[j] = v;
        }
    }
    if (tid < CPB) {
        long long ce = base + tid;
        ci = (ce < (long long)ncells) ? __builtin_nontemporal_load(&choice[ce]) : 0;
    }
}

__device__ __forceinline__ void stage_and_compute(
    float* __restrict__ sbuf, const vf4 (&r)[8], int myc,
    long long cellg, int ncells, int tid,
    float& a_loc, float& a_ce, float& a_obj, float& a_no,
    float& a_nob, float& a_nno)
{
    __syncthreads();                    // prev compute done reading sbuf
    #pragma unroll
    for (int j = 0; j < 8; ++j) {
        int k = j * T + tid;
        if (k < NF4) *(vf4*)&sbuf[k * 4] = r[j];
    }
    __syncthreads();                    // chunk visible
    if (tid < CPB && cellg < (long long)ncells) {
        const float* sp  = &sbuf[tid * NCH];
        const float* stt = &sbuf[CPB * NCH + tid * NCH];
        float p[NCH], t[NCH];
        #pragma unroll
        for (int i = 0; i < NCH / 2; ++i) {
            float2 v = *(const float2*)&sp[2 * i];  p[2*i] = v.x; p[2*i+1] = v.y;
        }
        #pragma unroll
        for (int i = 0; i < NCH / 2; ++i) {
            float2 w = *(const float2*)&stt[2 * i]; t[2*i] = w.x; t[2*i+1] = w.y;
        }
        bool csel = myc != 0;

        float tconf = t[4];
        bool  obj = tconf > 0.0f;
        float m = obj ? 1.0f : 0.0f;

        float pxy0 = csel ? p[0] : p[5];
        float pxy1 = csel ? p[1] : p[6];
        float pwh0 = csel ? p[2] : p[7];
        float pwh1 = csel ? p[3] : p[8];
        float pobj = csel ? p[4] : p[9];
        float txy0 = csel ? t[0] : t[5];
        float txy1 = csel ? t[1] : t[6];
        float twh0 = csel ? t[2] : t[7];
        float twh1 = csel ? t[3] : t[8];
        if (!obj) { twh0 = 1.0f; twh1 = 1.0f; }
        float tobj = csel ? tconf : t[9];

        float dx = pxy0 - txy0, dy = pxy1 - txy1;
        float dw = pwh0 - sqrtf(twh0), dh = pwh1 - sqrtf(twh1);
        a_loc += m * (0.5f * (dx*dx + dy*dy) + 0.5f * (dw*dw + dh*dh));

        float dob = pobj - tobj;
        a_obj += m * dob * dob;

        float nm = (tconf == 0.0f) ? 1.0f : 0.0f;
        float d4 = p[4] - tconf, d9 = p[9] - t[9];
        a_no += nm * (d4 * d4 + d9 * d9);

        a_nob += m;
        a_nno += nm;

        int   tcls  = 0;
        float tbest = t[10];
        #pragma unroll
        for (int i = 1; i < CC; ++i) {
            float v = t[10 + i];
            if (v > tbest) { tbest = v; tcls = i; }
        }
        float mx = p[10];
        #pragma unroll
        for (int i = 1; i < CC; ++i) mx = fmaxf(mx, p[10 + i]);
        float e[CC];
        float Z = 0.f;
        #pragma unroll
        for (int i = 0; i < CC; ++i) { e[i] = __expf(p[10+i] - mx); Z += e[i]; }
        float rZ = 1.0f / Z;
        float Z2 = 0.f, sm_t = 0.f;
        #pragma unroll
        for (int i = 0; i < CC; ++i) {
            float sm = e[i] * rZ;          // in (0,1] -> exp safe
            Z2 += __expf(sm);
            if (i == tcls) sm_t = sm;
        }
        a_ce += m * (__logf(Z2) - sm_t);
    }
}

__global__ __launch_bounds__(T) void yolo_main(
    const float* __restrict__ pred, const float* __restrict__ target,
    const int* __restrict__ choice, float* __restrict__ ws,
    int ncells, int nchunks)
{
    __shared__ float sbuf[2 * CPB * NCH];   // 30720 B: [pred chunk][target chunk]
    const int tid = threadIdx.x;

    float a_loc = 0.f, a_ce = 0.f, a_obj = 0.f, a_no = 0.f;
    float a_nob = 0.f, a_nno = 0.f;

    vf4 rA[8], rB[8];
    int ciA = 0, ciB = 0;
    int c = blockIdx.x;
    if (c < nchunks)        issue_chunk(pred, target, choice, c,        ncells, tid, rA, ciA);
    if (c + GRID < nchunks) issue_chunk(pred, target, choice, c + GRID, ncells, tid, rB, ciB);

    for (; c < nchunks; c += 2 * GRID) {
        // chunk c from rA; prefetch c+2G into rA before compute
        {
            int myc = ciA;
            long long cg = (long long)c * CPB + tid;
            __syncthreads();
            #pragma unroll
            for (int j = 0; j < 8; ++j) {
                int k = j * T + tid;
                if (k < NF4) *(vf4*)&sbuf[k * 4] = rA[j];
            }
            __syncthreads();
            if (c + 2 * GRID < nchunks)
                issue_chunk(pred, target, choice, c + 2 * GRID, ncells, tid, rA, ciA);
            // compute on sbuf (duplicated here to keep prefetch between the
            // barrier and compute)
            stage_compute_body:;
            if (tid < CPB && cg < (long long)ncells) {
                const float* sp  = &sbuf[tid * NCH];
                const float* stt = &sbuf[CPB * NCH + tid * NCH];
                float p[NCH], t[NCH];
                #pragma unroll
                for (int i = 0; i < NCH / 2; ++i) {
                    float2 v = *(const float2*)&sp[2 * i];  p[2*i] = v.x; p[2*i+1] = v.y;
                }
                #pragma unroll
                for (int i = 0; i < NCH / 2; ++i) {
                    float2 w = *(const float2*)&stt[2 * i]; t[2*i] = w.x; t[2*i+1] = w.y;
                }
                bool csel = myc != 0;
                float tconf = t[4];
                bool  obj = tconf > 0.0f;
                float m = obj ? 1.0f : 0.0f;
                float pxy0 = csel ? p[0] : p[5];
                float pxy1 = csel ? p[1] : p[6];
                float pwh0 = csel ? p[2] : p[7];
                float pwh1 = csel ? p[3] : p[8];
                float pobj = csel ? p[4] : p[9];
                float txy0 = csel ? t[0] : t[5];
                float txy1 = csel ? t[1] : t[6];
                float twh0 = csel ? t[2] : t[7];
                float twh1 = csel ? t[3] : t[8];
                if (!obj) { twh0 = 1.0f; twh1 = 1.0f; }
                float tobj = csel ? tconf : t[9];
                float dx = pxy0 - txy0, dy = pxy1 - txy1;
                float dw = pwh0 - sqrtf(twh0), dh = pwh1 - sqrtf(twh1);
                a_loc += m * (0.5f * (dx*dx + dy*dy) + 0.5f * (dw*dw + dh*dh));
                float dob = pobj - tobj;
                a_obj += m * dob * dob;
                float nm = (tconf == 0.0f) ? 1.0f : 0.0f;
                float d4 = p[4] - tconf, d9 = p[9] - t[9];
                a_no += nm * (d4 * d4 + d9 * d9);
                a_nob += m;
                a_nno += nm;
                int   tcls  = 0;
                float tbest = t[10];
                #pragma unroll
                for (int i = 1; i < CC; ++i) {
                    float v = t[10 + i];
                    if (v > tbest) { tbest = v; tcls = i; }
                }
                float mx = p[10];
                #pragma unroll
                for (int i = 1; i < CC; ++i) mx = fmaxf(mx, p[10 + i]);
                float e[CC];
                float Z = 0.f;
                #pragma unroll
                for (int i = 0; i < CC; ++i) { e[i] = __expf(p[10+i] - mx); Z += e[i]; }
                float rZ = 1.0f / Z;
                float Z2 = 0.f, sm_t = 0.f;
                #pragma unroll
                for (int i = 0; i < CC; ++i) {
                    float sm = e[i] * rZ;
                    Z2 += __expf(sm);
                    if (i == tcls) sm_t = sm;
                }
                a_ce += m * (__logf(Z2) - sm_t);
            }
        }
        // chunk c+GRID from rB; prefetch c+3G into rB before compute
        if (c + GRID < nchunks) {
            int myc = ciB;
            long long cg = (long long)(c + GRID) * CPB + tid;
            __syncthreads();
            #pragma unroll
            for (int j = 0; j < 8; ++j) {
                int k = j * T + tid;
                if (k < NF4) *(vf4*)&sbuf[k * 4] = rB[j];
            }
            __syncthreads();
            if (c + 3 * GRID < nchunks)
                issue_chunk(pred, target, choice, c + 3 * GRID, ncells, tid, rB, ciB);
            if (tid < CPB && cg < (long long)ncells) {
                const float* sp  = &sbuf[tid * NCH];
                const float* stt = &sbuf[CPB * NCH + tid * NCH];
                float p[NCH], t[NCH];
                #pragma unroll
                for (int i = 0; i < NCH / 2; ++i) {
                    float2 v = *(const float2*)&sp[2 * i];  p[2*i] = v.x; p[2*i+1] = v.y;
                }
                #pragma unroll
                for (int i = 0; i < NCH / 2; ++i) {
                    float2 w = *(const float2*)&stt[2 * i]; t[2*i] = w.x; t[2*i+1] = w.y;
                }
                bool csel = myc != 0;
                float tconf = t[4];
                bool  obj = tconf > 0.0f;
                float m = obj ? 1.0f : 0.0f;
                float pxy0 = csel ? p[0] : p[5];
                float pxy1 = csel ? p[1] : p[6];
                float pwh0 = csel ? p[2] : p[7];
                float pwh1 = csel ? p[3] : p[8];
                float pobj = csel ? p[4] : p[9];
                float txy0 = csel ? t[0] : t[5];
                float txy1 = csel ? t[1] : t[6];
                float twh0 = csel ? t[2] : t[7];
                float twh1 = csel ? t[3] : t[8];
                if (!obj) { twh0 = 1.0f; twh1 = 1.0f; }
                float tobj = csel ? tconf : t[9];
                float dx = pxy0 - txy0, dy = pxy1 - txy1;
                float dw = pwh0 - sqrtf(twh0), dh = pwh1 - sqrtf(twh1);
                a_loc += m * (0.5f * (dx*dx + dy*dy) + 0.5f * (dw*dw + dh*dh));
                float dob = pobj - tobj;
                a_obj += m * dob * dob;
                float nm = (tconf == 0.0f) ? 1.0f : 0.0f;
                float d4 = p[4] - tconf, d9 = p[9] - t[9];
                a_no += nm * (d4 * d4 + d9 * d9);
                a_nob += m;
                a_nno += nm;
                int   tcls  = 0;
                float tbest = t[10];
                #pragma unroll
                for (int i = 1; i < CC; ++i) {
                    float v = t[10 + i];
                    if (v > tbest) { tbest = v; tcls = i; }
                }
                float mx = p[10];
                #pragma unroll
                for (int i = 1; i < CC; ++i) mx = fmaxf(mx, p[10 + i]);
                float e[CC];
                float Z = 0.f;
                #pragma unroll
                for (int i = 0; i < CC; ++i) { e[i] = __expf(p[10+i] - mx); Z += e[i]; }
                float rZ = 1.0f / Z;
                float Z2 = 0.f, sm_t = 0.f;
                #pragma unroll
                for (int i = 0; i < CC; ++i) {
                    float sm = e[i] * rZ;
                    Z2 += __expf(sm);
                    if (i == tcls) sm_t = sm;
                }
                a_ce += m * (__logf(Z2) - sm_t);
            }
        }
    }

    // wave(64) shuffle reduction of the 6 accumulators
    #pragma unroll
    for (int off = 32; off > 0; off >>= 1) {
        a_loc += __shfl_down(a_loc, off);
        a_ce  += __shfl_down(a_ce,  off);
        a_obj += __shfl_down(a_obj, off);
        a_no  += __shfl_down(a_no,  off);
        a_nob += __shfl_down(a_nob, off);
        a_nno += __shfl_down(a_nno, off);
    }

    __shared__ float red[4][6];
    int wave = tid >> 6;
    int lane = tid & 63;
    if (lane == 0) {
        red[wave][0] = a_loc; red[wave][1] = a_ce;  red[wave][2] = a_obj;
        red[wave][3] = a_no;  red[wave][4] = a_nob; red[wave][5] = a_nno;
    }
    __syncthreads();
    if (tid < 6) {   // NO atomics: private row per block
        float v = red[0][tid] + red[1][tid] + red[2][tid] + red[3][tid];
        ws[(size_t)blockIdx.x * ROW + tid] = v;
    }
}

__global__ __launch_bounds__(256) void yolo_reduce(
    const float* __restrict__ ws, float* __restrict__ out, int nb)
{
    float s[6] = {0.f, 0.f, 0.f, 0.f, 0.f, 0.f};
    for (int b = threadIdx.x; b < nb; b += 256) {
        #pragma unroll
        for (int j = 0; j < 6; ++j) s[j] += ws[(size_t)b * ROW + j];
    }
    #pragma unroll
    for (int off = 32; off > 0; off >>= 1) {
        #pragma unroll
        for (int j = 0; j < 6; ++j) s[j] += __shfl_down(s[j], off);
    }
    __shared__ float red[4][6];
    int wave = threadIdx.x >> 6;
    int lane = threadIdx.x & 63;
    if (lane == 0) {
        #pragma unroll
        for (int j = 0; j < 6; ++j) red[wave][j] = s[j];
    }
    __syncthreads();
    if (threadIdx.x == 0) {
        float t[6];
        #pragma unroll
        for (int j = 0; j < 6; ++j)
            t[j] = red[0][j] + red[1][j] + red[2][j] + red[3][j];
        out[0] = 5.0f * t[0];                     // loc_loss  (L_COORD = 5)
        out[1] = t[1] / fmaxf(t[4], 1.0f);        // cls_loss
        out[2] = t[2];                            // obj_loss
        out[3] = 0.5f * t[3] / fmaxf(t[5], 1.0f); // noobj_loss (L_NOOBJ = 0.5)
    }
}

extern "C" void kernel_launch(void* const* d_in, const int* in_sizes, int n_in,
                              void* d_out, int out_size, void* d_ws, size_t ws_size,
                              hipStream_t stream) {
    const float* pred   = (const float*)d_in[0];
    const float* target = (const float*)d_in[1];
    const int*   choice = (const int*)d_in[2];
    float* out = (float*)d_out;
    float* ws  = (float*)d_ws;

    int ncells  = in_sizes[2];                   // BATCH * S * S = 802816
    int nchunks = (ncells + CPB - 1) / CPB;      // 6272 exactly
    int grid    = GRID < nchunks ? GRID : nchunks;
    // ws usage: GRID * ROW * 4 B = 32 KB; rows [0,grid) all written before read
    yolo_main<<<grid, T, 0, stream>>>(pred, target, choice, ws, ncells, nchunks);
    yolo_reduce<<<1, 256, 0, stream>>>(ws, out, grid);
}

// Round 9
// 193.433 us; speedup vs baseline: 1.0215x; 1.0215x over previous
//
#include <hip/hip_runtime.h>
#include <math.h>

// YOLO loss: pred/target (BATCH,7,7,30) f32, choice (BATCH,7,7) i32
// -> 4 scalars (loc, cls, obj, noobj).
// Round-9 = revert to round-7 (best: 193.8us total). Round-8's prefetch
// depth-2 was neutral-to-negative -> burst-gap theory falsified; the
// nt-load read stream is at its structural ~3.5 TB/s ceiling and the
// remaining bench time is harness ws-poison fills (56us x several,
// 385 MB @ 6.8 TB/s), outside kernel control.
// Final structure: persistent blocks + VGPR prefetch (r5) + NON-TEMPORAL
// staging loads (r7, the big win: L1-allocation bypass, 75->~50us) +
// coalesced float4->LDS staging (r2) + atomic-free reduction (r3).

typedef float vf4 __attribute__((ext_vector_type(4)));   // nt-load compatible

constexpr int NCH = 30;    // 5*B + C
constexpr int CC  = 20;    // classes
constexpr int ROW = 8;     // floats per block's partial row (32 B)
constexpr int T   = 256;   // threads per block (4 waves)
constexpr int CPB = 128;   // cells per chunk
constexpr int NF4 = CPB * NCH * 2 / 4;  // 1920 vf4 per chunk (pred+target)
constexpr int HF4 = NF4 / 2;            // 960: pred/target boundary
constexpr int GRID = 1280; // 5 blocks/CU * 256 CU

__device__ __forceinline__ void issue_chunk(
    const float* __restrict__ pred, const float* __restrict__ target,
    const int* __restrict__ choice, int cc, int ncells, int tid,
    vf4 (&r)[8], int& ci)
{
    long long base = (long long)cc * CPB;
    if (base + CPB <= (long long)ncells) {
        const vf4* Pb = (const vf4*)(pred + base * NCH);
        const vf4* Tb = (const vf4*)(target + base * NCH);
        #pragma unroll
        for (int j = 0; j < 8; ++j) {
            int k = j * T + tid;            // guards wave-uniform (T mult of 64)
            if (k < NF4)
                r[j] = (k < HF4) ? __builtin_nontemporal_load(&Pb[k])
                                 : __builtin_nontemporal_load(&Tb[k - HF4]);
        }
    } else {
        int nfl = (int)(ncells - base) * NCH;   // valid floats per array
        const float* Pf = pred + base * NCH;
        const float* Tf = target + base * NCH;
        #pragma unroll
        for (int j = 0; j < 8; ++j) {
            int k = j * T + tid;
            vf4 v = (vf4)(0.f, 0.f, 0.f, 0.f);
            if (k < NF4) {
                int kk = (k < HF4) ? k : k - HF4;
                const float* src = (k < HF4) ? Pf : Tf;
                int b = 4 * kk;
                if (b + 0 < nfl) v.x = src[b + 0];
                if (b + 1 < nfl) v.y = src[b + 1];
                if (b + 2 < nfl) v.z = src[b + 2];
                if (b + 3 < nfl) v.w = src[b + 3];
            }
            r[j] = v;
        }
    }
    if (tid < CPB) {
        long long ce = base + tid;
        ci = (ce < (long long)ncells) ? __builtin_nontemporal_load(&choice[ce]) : 0;
    }
}

__global__ __launch_bounds__(T) void yolo_main(
    const float* __restrict__ pred, const float* __restrict__ target,
    const int* __restrict__ choice, float* __restrict__ ws,
    int ncells, int nchunks)
{
    __shared__ float sbuf[2 * CPB * NCH];   // 30720 B: [pred chunk][target chunk]
    const int tid = threadIdx.x;

    float a_loc = 0.f, a_ce = 0.f, a_obj = 0.f, a_no = 0.f;
    float a_nob = 0.f, a_nno = 0.f;

    vf4 r[8];
    int ci = 0;
    int c = blockIdx.x;
    if (c < nchunks) issue_chunk(pred, target, choice, c, ncells, tid, r, ci);

    for (; c < nchunks; c += GRID) {
        __syncthreads();                    // prev compute done reading sbuf
        #pragma unroll
        for (int j = 0; j < 8; ++j) {
            int k = j * T + tid;
            if (k < NF4) *(vf4*)&sbuf[k * 4] = r[j];
        }
        int myc = ci;
        __syncthreads();                    // chunk c visible

        int cn = c + GRID;                  // PREFETCH next chunk before compute
        if (cn < nchunks) issue_chunk(pred, target, choice, cn, ncells, tid, r, ci);

        if (tid < CPB && (long long)c * CPB + tid < ncells) {
            const float* sp  = &sbuf[tid * NCH];
            const float* stt = &sbuf[CPB * NCH + tid * NCH];
            float p[NCH], t[NCH];
            #pragma unroll
            for (int i = 0; i < NCH / 2; ++i) {
                float2 v = *(const float2*)&sp[2 * i];  p[2*i] = v.x; p[2*i+1] = v.y;
            }
            #pragma unroll
            for (int i = 0; i < NCH / 2; ++i) {
                float2 w = *(const float2*)&stt[2 * i]; t[2*i] = w.x; t[2*i+1] = w.y;
            }
            bool csel = myc != 0;

            float tconf = t[4];
            bool  obj = tconf > 0.0f;
            float m = obj ? 1.0f : 0.0f;

            float pxy0 = csel ? p[0] : p[5];
            float pxy1 = csel ? p[1] : p[6];
            float pwh0 = csel ? p[2] : p[7];
            float pwh1 = csel ? p[3] : p[8];
            float pobj = csel ? p[4] : p[9];
            float txy0 = csel ? t[0] : t[5];
            float txy1 = csel ? t[1] : t[6];
            float twh0 = csel ? t[2] : t[7];
            float twh1 = csel ? t[3] : t[8];
            if (!obj) { twh0 = 1.0f; twh1 = 1.0f; }
            float tobj = csel ? tconf : t[9];

            float dx = pxy0 - txy0, dy = pxy1 - txy1;
            float dw = pwh0 - sqrtf(twh0), dh = pwh1 - sqrtf(twh1);
            a_loc += m * (0.5f * (dx*dx + dy*dy) + 0.5f * (dw*dw + dh*dh));

            float dob = pobj - tobj;
            a_obj += m * dob * dob;

            float nm = (tconf == 0.0f) ? 1.0f : 0.0f;
            float d4 = p[4] - tconf, d9 = p[9] - t[9];
            a_no += nm * (d4 * d4 + d9 * d9);

            a_nob += m;
            a_nno += nm;

            int   tcls  = 0;
            float tbest = t[10];
            #pragma unroll
            for (int i = 1; i < CC; ++i) {
                float v = t[10 + i];
                if (v > tbest) { tbest = v; tcls = i; }
            }
            float mx = p[10];
            #pragma unroll
            for (int i = 1; i < CC; ++i) mx = fmaxf(mx, p[10 + i]);
            float e[CC];
            float Z = 0.f;
            #pragma unroll
            for (int i = 0; i < CC; ++i) { e[i] = __expf(p[10+i] - mx); Z += e[i]; }
            float rZ = 1.0f / Z;
            float Z2 = 0.f, sm_t = 0.f;
            #pragma unroll
            for (int i = 0; i < CC; ++i) {
                float sm = e[i] * rZ;          // in (0,1] -> exp safe
                Z2 += __expf(sm);
                if (i == tcls) sm_t = sm;
            }
            a_ce += m * (__logf(Z2) - sm_t);
        }
    }

    // wave(64) shuffle reduction of the 6 accumulators
    #pragma unroll
    for (int off = 32; off > 0; off >>= 1) {
        a_loc += __shfl_down(a_loc, off);
        a_ce  += __shfl_down(a_ce,  off);
        a_obj += __shfl_down(a_obj, off);
        a_no  += __shfl_down(a_no,  off);
        a_nob += __shfl_down(a_nob, off);
        a_nno += __shfl_down(a_nno, off);
    }

    __shared__ float red[4][6];
    int wave = tid >> 6;
    int lane = tid & 63;
    if (lane == 0) {
        red[wave][0] = a_loc; red[wave][1] = a_ce;  red[wave][2] = a_obj;
        red[wave][3] = a_no;  red[wave][4] = a_nob; red[wave][5] = a_nno;
    }
    __syncthreads();
    if (tid < 6) {   // NO atomics: private row per block
        float v = red[0][tid] + red[1][tid] + red[2][tid] + red[3][tid];
        ws[(size_t)blockIdx.x * ROW + tid] = v;
    }
}

__global__ __launch_bounds__(256) void yolo_reduce(
    const float* __restrict__ ws, float* __restrict__ out, int nb)
{
    float s[6] = {0.f, 0.f, 0.f, 0.f, 0.f, 0.f};
    for (int b = threadIdx.x; b < nb; b += 256) {
        #pragma unroll
        for (int j = 0; j < 6; ++j) s[j] += ws[(size_t)b * ROW + j];
    }
    #pragma unroll
    for (int off = 32; off > 0; off >>= 1) {
        #pragma unroll
        for (int j = 0; j < 6; ++j) s[j] += __shfl_down(s[j], off);
    }
    __shared__ float red[4][6];
    int wave = threadIdx.x >> 6;
    int lane = threadIdx.x & 63;
    if (lane == 0) {
        #pragma unroll
        for (int j = 0; j < 6; ++j) red[wave][j] = s[j];
    }
    __syncthreads();
    if (threadIdx.x == 0) {
        float t[6];
        #pragma unroll
        for (int j = 0; j < 6; ++j)
            t[j] = red[0][j] + red[1][j] + red[2][j] + red[3][j];
        out[0] = 5.0f * t[0];                     // loc_loss  (L_COORD = 5)
        out[1] = t[1] / fmaxf(t[4], 1.0f);        // cls_loss
        out[2] = t[2];                            // obj_loss
        out[3] = 0.5f * t[3] / fmaxf(t[5], 1.0f); // noobj_loss (L_NOOBJ = 0.5)
    }
}

extern "C" void kernel_launch(void* const* d_in, const int* in_sizes, int n_in,
                              void* d_out, int out_size, void* d_ws, size_t ws_size,
                              hipStream_t stream) {
    const float* pred   = (const float*)d_in[0];
    const float* target = (const float*)d_in[1];
    const int*   choice = (const int*)d_in[2];
    float* out = (float*)d_out;
    float* ws  = (float*)d_ws;

    int ncells  = in_sizes[2];                   // BATCH * S * S = 802816
    int nchunks = (ncells + CPB - 1) / CPB;      // 6272 exactly
    int grid    = GRID < nchunks ? GRID : nchunks;
    // ws usage: GRID * ROW * 4 B = 40 KB; rows [0,grid) all written before read
    yolo_main<<<grid, T, 0, stream>>>(pred, target, choice, ws, ncells, nchunks);
    yolo_reduce<<<1, 256, 0, stream>>>(ws, out, grid);
}